// Round 14
// baseline (136.833 us; speedup 1.0000x reference)
//
#include <hip/hip_runtime.h>

typedef __attribute__((ext_vector_type(4))) float f32x4;
typedef __attribute__((ext_vector_type(8))) short s16x8;
typedef unsigned short u16;

#define DEVI __device__ __forceinline__

// fp32 -> bf16 round-to-nearest-even
DEVI u16 f2bf(float f) {
    union { float f; unsigned int u; } v; v.f = f;
    unsigned int r = v.u + 0x7FFFu + ((v.u >> 16) & 1u);
    return (u16)(r >> 16);
}
DEVI float bf2f(u16 b) {
    union { unsigned int u; float f; } v; v.u = ((unsigned int)b) << 16;
    return v.f;
}

typedef __attribute__((address_space(1))) void gv_t;   // global
typedef __attribute__((address_space(3))) void sv_t;   // LDS

#define GLOAD16(SRC, DST) __builtin_amdgcn_global_load_lds( \
    (gv_t*)(SRC), (sv_t*)(DST), 16, 0, 0)

DEVI f32x4 mfma_bf16(s16x8 a, s16x8 b, f32x4 c) {
    return __builtin_amdgcn_mfma_f32_16x16x32_bf16(a, b, c, 0, 0, 0);
}

// ---------------------------------------------------------------------------
// fp32 -> bf16: x, wq, wk, wv. (wo rides inside the attn launch, where BW
// is idle -- R11 measured riders in gemm1 cost the full 11 us.)
// ---------------------------------------------------------------------------
__global__ void cvt1_kernel(
    const float* __restrict__ x,  const float* __restrict__ wq, const float* __restrict__ wk,
    const float* __restrict__ wv,
    u16* __restrict__ xb, u16* __restrict__ wqb, u16* __restrict__ wkb,
    u16* __restrict__ wvb)
{
    int id = blockIdx.x * 256 + threadIdx.x;   // 0 .. 4423680-1 (f32x4 units)
    const float* s; u16* d; int off;
    if      (id < 737280)  { s = x;  d = xb;  off = id; }
    else if (id < 3686400) { s = wq; d = wqb; off = id - 737280; }
    else if (id < 4055040) { s = wk; d = wkb; off = id - 3686400; }
    else                   { s = wv; d = wvb; off = id - 4055040; }
    f32x4 v = *(const f32x4*)(s + (size_t)off * 4);
    union { u16 u[4]; unsigned long long ll; } o;
    #pragma unroll
    for (int j = 0; j < 4; ++j) o.u[j] = f2bf(v[j]);
    *(unsigned long long*)(d + (size_t)off * 4) = o.ll;
}

// ---------------------------------------------------------------------------
// NT GEMM, split-K, m97-EXACT structure (R10: best measured, ~640 TF).
// 256 threads, 4 waves of 64x64, 128x128 tile, BK=64, single 32 KB LDS buf,
// 2-barrier K-loop; pipelining = implicit cross-block wave overlap (~4/CU).
// bounds(256,3): no spill (VGPR 64 arch + 64 acc). XOR chunk swizzle.
// XCD map: 8 consecutive M-tiles of one N-stripe per XCD.
// ---------------------------------------------------------------------------
__global__ __launch_bounds__(256, 3) void gemm_m97(
    const u16* __restrict__ A, int lda, int kit, int ntot,
    const u16* __restrict__ W0, int t0, int n0, int c0,
    const u16* __restrict__ W1, int t1, int n1, int c1,
    const u16* __restrict__ W2, int t2, int n2, int c2,
    u16* __restrict__ C, int ldc, long long cstride)
{
    __shared__ u16 Als[128 * 64];
    __shared__ u16 Bls[128 * 64];

    const int lin = blockIdx.x;
    const int xc  = lin & 7;
    const int mm  = lin >> 3;
    const int nbl = xc + 8 * (mm >> 3);
    const int yt  = mm & 7;
    if (nbl >= ntot) return;   // uniform per block; no barriers executed

    const int tid  = threadIdx.x;
    const int lane = tid & 63;
    const int wid  = tid >> 6;          // 0..3
    const int li   = lane & 15;
    const int lg   = lane >> 4;
    const int m0   = yt * 128;

    const u16* W; int nt0, nsz, cb;
    if (nbl < t0)           { W = W0; nt0 = nbl * 128;             nsz = n0; cb = c0; }
    else if (nbl < t0 + t1) { W = W1; nt0 = (nbl - t0) * 128;      nsz = n1; cb = c1; }
    else                    { W = W2; nt0 = (nbl - t0 - t1) * 128; nsz = n2; cb = c2; }

    const int z  = blockIdx.z;
    const int S  = gridDim.z;
    const int it0 = (z * kit) / S;
    const int it1 = ((z + 1) * kit) / S;
    u16* Cp = C + (long long)z * cstride;

    const int wm = (wid >> 1) * 64;
    const int wn = (wid & 1) * 64;

    f32x4 acc[4][4];
    #pragma unroll
    for (int mi = 0; mi < 4; ++mi)
        #pragma unroll
        for (int ni = 0; ni < 4; ++ni)
            acc[mi][ni] = (f32x4){0.f, 0.f, 0.f, 0.f};

    const int srow = tid >> 3;                 // 0..31 (row within 32-row slab)
    const int slc  = (tid & 7) ^ (srow & 7);   // inverse-swizzled source chunk

    for (int it = it0; it < it1; ++it) {
        const int k0 = it * 64;
        #pragma unroll
        for (int s_ = 0; s_ < 4; ++s_) {
            const u16* sa = A + (size_t)(m0 + s_ * 32 + srow) * lda + k0 + slc * 8;
            GLOAD16(sa, &Als[(s_ * 256 + tid) * 8]);
        }
        #pragma unroll
        for (int s_ = 0; s_ < 4; ++s_) {
            int wr = nt0 + s_ * 32 + srow;
            if (wr > nsz - 1) wr = nsz - 1;    // ragged-N clamp (stores guarded)
            const u16* sb = W + (size_t)wr * lda + k0 + slc * 8;
            GLOAD16(sb, &Bls[(s_ * 256 + tid) * 8]);
        }
        __syncthreads();

        s16x8 af[4][2], bfv[4][2];
        #pragma unroll
        for (int mi = 0; mi < 4; ++mi)
            #pragma unroll
            for (int kc = 0; kc < 2; ++kc) {
                int row = wm + mi * 16 + li;
                int ch  = (kc * 4 + lg) ^ (row & 7);
                af[mi][kc] = *(const s16x8*)&Als[row * 64 + ch * 8];
            }
        #pragma unroll
        for (int ni = 0; ni < 4; ++ni)
            #pragma unroll
            for (int kc = 0; kc < 2; ++kc) {
                int row = wn + ni * 16 + li;
                int ch  = (kc * 4 + lg) ^ (row & 7);
                bfv[ni][kc] = *(const s16x8*)&Bls[row * 64 + ch * 8];
            }
        #pragma unroll
        for (int mi = 0; mi < 4; ++mi)
            #pragma unroll
            for (int ni = 0; ni < 4; ++ni)
                #pragma unroll
                for (int kc = 0; kc < 2; ++kc)
                    acc[mi][ni] = mfma_bf16(af[mi][kc], bfv[ni][kc], acc[mi][ni]);
        __syncthreads();
    }

    #pragma unroll
    for (int ni = 0; ni < 4; ++ni) {
        int colr = nt0 + wn + ni * 16 + li;
        if (colr < nsz) {
            #pragma unroll
            for (int mi = 0; mi < 4; ++mi)
                #pragma unroll
                for (int r = 0; r < 4; ++r) {
                    int row = m0 + wm + mi * 16 + lg * 4 + r;
                    Cp[(size_t)row * ldc + cb + colr] = f2bf(acc[mi][ni][r]);
                }
        }
    }
}

// ---------------------------------------------------------------------------
// RoPE + bias + bf16 convert from 3 bf16 split-K partials. Vectorized;
// V written transposed VT[kvh][d][s] for contiguous attn PV fragments.
// ---------------------------------------------------------------------------
__global__ void rope_kernel(const u16* __restrict__ qkvp,
                            const float* __restrict__ qb, const float* __restrict__ kb,
                            const float* __restrict__ vb,
                            u16* __restrict__ qo, u16* __restrict__ ko, u16* __restrict__ vt)
{
    const long long PST = 1024LL * 5120;
    int id = blockIdx.x * 256 + threadIdx.x;   // 1024 * 352
    int s  = id / 352;
    int g  = id % 352;
    const u16* r0 = qkvp + (size_t)s * 5120;

    if (g < 288) {                      // q (g<256) or k
        bool isq = g < 256;
        int gg   = isq ? g : g - 256;
        int hh   = gg >> 2;
        int dg   = gg & 3;
        int col0 = (isq ? 0 : 4096) + hh * 64 + dg * 8;
        int bcol = isq ? col0 : col0 - 4096;
        const float* bias = isq ? qb : kb;

        float t1[8], t2[8];
        #pragma unroll
        for (int e = 0; e < 8; ++e) { t1[e] = bias[bcol + e]; t2[e] = bias[bcol + 32 + e]; }
        #pragma unroll
        for (int p = 0; p < 3; ++p) {
            s16x8 lo = *(const s16x8*)(r0 + col0 + p * PST);
            s16x8 hi = *(const s16x8*)(r0 + col0 + 32 + p * PST);
            #pragma unroll
            for (int e = 0; e < 8; ++e) {
                t1[e] += bf2f((u16)lo[e]);
                t2[e] += bf2f((u16)hi[e]);
            }
        }
        float sc = isq ? 0.125f : 1.0f;    // fold HD^-0.5 into q
        s16x8 o1, o2;
        #pragma unroll
        for (int e = 0; e < 8; ++e) {
            int d = dg * 8 + e;
            float ang = (float)s * exp2f((float)d * -0.5373314f);
            float sn, cs;
            sincosf(ang, &sn, &cs);
            o1[e] = (short)f2bf((t1[e] * cs - t2[e] * sn) * sc);
            o2[e] = (short)f2bf((t1[e] * sn + t2[e] * cs) * sc);
        }
        u16* dst = isq ? qo : ko;
        int ldd  = isq ? 4096 : 512;
        *(s16x8*)(dst + (size_t)s * ldd + bcol)      = o1;
        *(s16x8*)(dst + (size_t)s * ldd + bcol + 32) = o2;
    } else {                            // v: sum + bias, write TRANSPOSED
        int gg   = g - 288;             // 0..63  (global v-col group)
        int col0 = 4608 + gg * 8;
        float t[8];
        #pragma unroll
        for (int e = 0; e < 8; ++e) t[e] = vb[gg * 8 + e];
        #pragma unroll
        for (int p = 0; p < 3; ++p) {
            s16x8 v = *(const s16x8*)(r0 + col0 + p * PST);
            #pragma unroll
            for (int e = 0; e < 8; ++e) t[e] += bf2f((u16)v[e]);
        }
        #pragma unroll
        for (int e = 0; e < 8; ++e)
            vt[((size_t)(gg * 8 + e)) * 1024 + s] = f2bf(t[e]);
    }
}

// ---------------------------------------------------------------------------
// out = sum of 4 bf16 split-K partials + bias (fp32)
// ---------------------------------------------------------------------------
__global__ void reduce_out_kernel(const u16* __restrict__ parts,
                                  const float* __restrict__ bias,
                                  float* __restrict__ out)
{
    int id = blockIdx.x * 256 + threadIdx.x;      // 0..368639 (8-elem groups)
    const long long stride = 1024LL * 2880;
    long long base = (long long)id * 8;
    float s[8];
    #pragma unroll
    for (int j = 0; j < 8; ++j) s[j] = 0.f;
    #pragma unroll
    for (int p = 0; p < 4; ++p) {
        s16x8 v = *(const s16x8*)(parts + p * stride + base);
        #pragma unroll
        for (int j = 0; j < 8; ++j) s[j] += bf2f((u16)v[j]);
    }
    int cb = (int)(base % 2880);
    f32x4 b0 = *(const f32x4*)(bias + cb);
    f32x4 b1 = *(const f32x4*)(bias + cb + 4);
    f32x4 o0 = {s[0] + b0[0], s[1] + b0[1], s[2] + b0[2], s[3] + b0[3]};
    f32x4 o1 = {s[4] + b1[0], s[5] + b1[1], s[6] + b1[2], s[7] + b1[3]};
    *(f32x4*)(out + base)     = o0;
    *(f32x4*)(out + base + 4) = o1;
}

// ---------------------------------------------------------------------------
// Sliding-window GQA attention with sinks, 2 q-blocks per block (128 rows):
// adjacent q-blocks share 2 of 3 KV tiles -> 4 staged K-tiles (vs 6) and
// V-frags loaded once per tile for both groups. Group g in {0,1} owns rows
// qp*128 + g*64 + w*16..; g is active for tile index t in [g, g+2]
// (jt = 2*qp - 2 + t). Blocks with x >= 64 are wo-cvt riders (y==0 only):
// attn is compute/latency-bound, so the 71 MB wo stream rides its idle BW.
// ---------------------------------------------------------------------------
__global__ __launch_bounds__(256, 2) void attn_kernel(
    const u16* __restrict__ Q, const u16* __restrict__ Kb, const u16* __restrict__ VT,
    const float* __restrict__ sinks, u16* __restrict__ Ob,
    const float* __restrict__ cvsrc, u16* __restrict__ cvdst)
{
    if (blockIdx.x >= 64) {             // wo-cvt rider (720 blocks on y==0)
        if (blockIdx.y == 0) {
            const int cb_  = blockIdx.x - 64;       // 0..719
            const int step = 720 * 256;             // f32x4 stride
            int idx = cb_ * 256 + threadIdx.x;
            #pragma unroll 4
            for (int i = 0; i < 16; ++i) {
                f32x4 v = *(const f32x4*)(cvsrc + (size_t)idx * 4);
                union { u16 u[4]; unsigned long long ll; } o;
                #pragma unroll
                for (int j = 0; j < 4; ++j) o.u[j] = f2bf(v[j]);
                *(unsigned long long*)(cvdst + (size_t)idx * 4) = o.ll;
                idx += step;
            }
        }
        return;
    }

    __shared__ u16 Kls[64 * 64];
    __shared__ u16 Pls[4][16 * 72];

    const int h    = blockIdx.x;
    const int qp   = blockIdx.y;        // 0..7 (128 q-rows each)
    const int kvh  = h >> 3;
    const int tid  = threadIdx.x;
    const int lane = tid & 63;
    const int w    = tid >> 6;
    const int li   = lane & 15;
    const int lg   = lane >> 4;

    s16x8 aq[2][2];
    #pragma unroll
    for (int g = 0; g < 2; ++g) {
        const u16* qrow = Q + ((size_t)(qp * 128 + g * 64 + w * 16 + li) * 64 + h) * 64 + lg * 8;
        aq[g][0] = *(const s16x8*)(qrow);
        aq[g][1] = *(const s16x8*)(qrow + 32);
    }

    const float snk = sinks[h];
    float m_run[2][4], l_run[2][4];
    f32x4 oacc[2][4];
    #pragma unroll
    for (int g = 0; g < 2; ++g) {
        #pragma unroll
        for (int r = 0; r < 4; ++r) { m_run[g][r] = snk; l_run[g][r] = 1.0f; }
        #pragma unroll
        for (int ni = 0; ni < 4; ++ni) oacc[g][ni] = (f32x4){0.f, 0.f, 0.f, 0.f};
    }

    const int srow = tid >> 3;
    const int slc  = (tid & 7) ^ (srow & 7);

    for (int t = 0; t < 4; ++t) {
        int jt = qp * 2 - 2 + t;
        if (jt < 0) continue;
        int j0 = jt * 64;

        #pragma unroll
        for (int it = 0; it < 2; ++it) {
            const u16* src = Kb + ((size_t)(j0 + it * 32 + srow) * 8 + kvh) * 64 + slc * 8;
            GLOAD16(src, &Kls[(it * 256 + w * 64) * 8]);
        }

        // V fragments (shared by both groups), P-independent: issue early.
        s16x8 bv[2][4];
        #pragma unroll
        for (int kc = 0; kc < 2; ++kc)
            #pragma unroll
            for (int ni = 0; ni < 4; ++ni)
                bv[kc][ni] = *(const s16x8*)(VT +
                    ((size_t)(kvh * 64 + ni * 16 + li)) * 1024 + j0 + kc * 32 + lg * 8);

        __syncthreads();   // staging done; all waves past previous tile

        #pragma unroll
        for (int g = 0; g < 2; ++g) {
            if (t < g || t > g + 2) continue;   // group active for t in [g, g+2]

            f32x4 sc[4];
            #pragma unroll
            for (int nf = 0; nf < 4; ++nf) {
                sc[nf] = (f32x4){0.f, 0.f, 0.f, 0.f};
                #pragma unroll
                for (int kc = 0; kc < 2; ++kc) {
                    int row = nf * 16 + li;
                    int ch  = (kc * 4 + lg) ^ (row & 7);
                    s16x8 bk = *(const s16x8*)&Kls[row * 64 + ch * 8];
                    sc[nf] = mfma_bf16(aq[g][kc], bk, sc[nf]);
                }
            }

            #pragma unroll
            for (int r = 0; r < 4; ++r) {
                const int qg = qp * 128 + g * 64 + w * 16 + lg * 4 + r;
                float mx = -1e30f;
                #pragma unroll
                for (int nf = 0; nf < 4; ++nf) {
                    int jg = j0 + nf * 16 + li;
                    bool ok = (jg <= qg) && (qg - jg < 128);
                    float v = ok ? sc[nf][r] : -1e30f;
                    sc[nf][r] = v;
                    mx = fmaxf(mx, v);
                }
                #pragma unroll
                for (int off = 1; off < 16; off <<= 1)
                    mx = fmaxf(mx, __shfl_xor(mx, off));
                float mnew = fmaxf(m_run[g][r], mx);
                float corr = __expf(m_run[g][r] - mnew);
                m_run[g][r] = mnew;
                float rs = 0.f;
                #pragma unroll
                for (int nf = 0; nf < 4; ++nf) {
                    float p = __expf(sc[nf][r] - mnew);
                    rs += p;
                    Pls[w][(lg * 4 + r) * 72 + nf * 16 + li] = f2bf(p);
                }
                #pragma unroll
                for (int off = 1; off < 16; off <<= 1)
                    rs += __shfl_xor(rs, off);
                l_run[g][r] = l_run[g][r] * corr + rs;
                #pragma unroll
                for (int ni = 0; ni < 4; ++ni) oacc[g][ni][r] *= corr;
            }
            __syncthreads();   // P writes drained; all waves' QK(g) done

            #pragma unroll
            for (int kc = 0; kc < 2; ++kc) {
                s16x8 pa = *(const s16x8*)&Pls[w][li * 72 + kc * 32 + lg * 8];
                #pragma unroll
                for (int ni = 0; ni < 4; ++ni)
                    oacc[g][ni] = mfma_bf16(pa, bv[kc][ni], oacc[g][ni]);
            }
        }
    }

    #pragma unroll
    for (int g = 0; g < 2; ++g)
        #pragma unroll
        for (int r = 0; r < 4; ++r) {
            float inv = 1.0f / l_run[g][r];
            #pragma unroll
            for (int ni = 0; ni < 4; ++ni)
                Ob[((size_t)(qp * 128 + g * 64 + w * 16 + lg * 4 + r) * 64 + h) * 64
                   + ni * 16 + li] = f2bf(oacc[g][ni][r] * inv);
        }
}

// ---------------------------------------------------------------------------
extern "C" void kernel_launch(void* const* d_in, const int* in_sizes, int n_in,
                              void* d_out, int out_size, void* d_ws, size_t ws_size,
                              hipStream_t stream)
{
    const float* x     = (const float*)d_in[0];
    const float* wq_w  = (const float*)d_in[1];
    const float* wq_b  = (const float*)d_in[2];
    const float* wk_w  = (const float*)d_in[3];
    const float* wk_b  = (const float*)d_in[4];
    const float* wv_w  = (const float*)d_in[5];
    const float* wv_b  = (const float*)d_in[6];
    const float* wo_w  = (const float*)d_in[7];
    const float* wo_b  = (const float*)d_in[8];
    const float* sinks = (const float*)d_in[9];

    char* ws = (char*)d_ws;
    // Layout (peak 112.1 MB; 117.9 proven available):
    //   [0, 35,389,440)           xb|wqb|wkb|wvb        (cvt1 -> gemm1)
    //       after rope overlays:  qr@0|kr|vt|attb       (rope -> gemm2)
    //   [35,389,440, 66,846,720)  qkvp 3 bf16 partials  (gemm1 -> rope)
    //   [58,982,400, 88,473,600)  oprt 4 bf16 partials  (gemm2 -> reduce)
    //   [88,473,600, 112,066,560) wob                   (attn-launch cvt -> gemm2)
    u16*   xb   = (u16*)(ws + 0);
    u16*   wqb  = (u16*)(ws + 5898240ULL);
    u16*   wkb  = (u16*)(ws + 29491200ULL);
    u16*   wvb  = (u16*)(ws + 32440320ULL);
    u16*   qkvp = (u16*)(ws + 35389440ULL);      // 3 bf16 partials, stride 1024*5120
    u16*   qr   = (u16*)(ws + 0);
    u16*   kr   = (u16*)(ws + 8388608ULL);
    u16*   vt   = (u16*)(ws + 9437184ULL);       // VT [8*64][1024] bf16, 1 MB
    u16*   attb = (u16*)(ws + 10485760ULL);
    u16*   oprt = (u16*)(ws + 58982400ULL);      // 4 bf16 partials, stride 1024*2880
    u16*   wob  = (u16*)(ws + 88473600ULL);

    (void)in_sizes; (void)n_in; (void)out_size; (void)ws_size;

    // 1) bf16 conversions: x, wq, wk, wv
    cvt1_kernel<<<17280, 256, 0, stream>>>(x, wq_w, wk_w, wv_w, xb, wqb, wkb, wvb);
    // 2) fused QKV projection, split-K=3 -> 3 bf16 partials [1024][5120]
    //    960 blocks, ~4/CU (R10 config: best measured GEMM)
    gemm_m97<<<dim3(320, 1, 3), 256, 0, stream>>>(xb, 2880, 45, 40,
        wqb, 32, 4096, 0,
        wkb, 4, 512, 4096,
        wvb, 4, 512, 4608,
        qkvp, 5120, 1024LL * 5120);
    // 3) RoPE + partial-sum + bias + convert; V written transposed (VT)
    rope_kernel<<<1408, 256, 0, stream>>>(qkvp, wq_b, wk_b, wv_b, qr, kr, vt);
    // 4) attention (2 q-blocks/block) + wo-cvt riders -> attb bf16 [1024][4096]
    //    grid: 64 heads + 720 riders (y==0) x 8 q-pairs
    attn_kernel<<<dim3(784, 8), 256, 0, stream>>>(qr, kr, vt, sinks, attb,
                                                  wo_w, wob);
    // 5) output projection, split-K=4 -> 4 bf16 partials [1024][2880]
    gemm_m97<<<dim3(192, 1, 4), 256, 0, stream>>>(attb, 4096, 64, 23,
        wob, 23, 2880, 0,
        wob, 0, 0, 0,
        wob, 0, 0, 0,
        oprt, 2880, 1024LL * 2880);
    // 6) reduce 4 partials + bias -> d_out fp32 [1024][2880]
    reduce_out_kernel<<<1440, 256, 0, stream>>>(oprt, wo_b, (float*)d_out);
}

// Round 15
// 129.458 us; speedup vs baseline: 1.0570x; 1.0570x over previous
//
#include <hip/hip_runtime.h>

typedef __attribute__((ext_vector_type(4))) float f32x4;
typedef __attribute__((ext_vector_type(8))) short s16x8;
typedef unsigned short u16;

#define DEVI __device__ __forceinline__

// fp32 -> bf16 round-to-nearest-even
DEVI u16 f2bf(float f) {
    union { float f; unsigned int u; } v; v.f = f;
    unsigned int r = v.u + 0x7FFFu + ((v.u >> 16) & 1u);
    return (u16)(r >> 16);
}
DEVI float bf2f(u16 b) {
    union { unsigned int u; float f; } v; v.u = ((unsigned int)b) << 16;
    return v.f;
}

typedef __attribute__((address_space(1))) void gv_t;   // global
typedef __attribute__((address_space(3))) void sv_t;   // LDS

#define GLOAD16(SRC, DST) __builtin_amdgcn_global_load_lds( \
    (gv_t*)(SRC), (sv_t*)(DST), 16, 0, 0)

DEVI f32x4 mfma_bf16(s16x8 a, s16x8 b, f32x4 c) {
    return __builtin_amdgcn_mfma_f32_16x16x32_bf16(a, b, c, 0, 0, 0);
}

// ---------------------------------------------------------------------------
// fp32 -> bf16: x, wq, wk, wv only. wo is converted inside the GEMM1 launch.
// ---------------------------------------------------------------------------
__global__ void cvt1_kernel(
    const float* __restrict__ x,  const float* __restrict__ wq, const float* __restrict__ wk,
    const float* __restrict__ wv,
    u16* __restrict__ xb, u16* __restrict__ wqb, u16* __restrict__ wkb,
    u16* __restrict__ wvb)
{
    int id = blockIdx.x * 256 + threadIdx.x;   // 0 .. 4423680-1 (f32x4 units)
    const float* s; u16* d; int off;
    if      (id < 737280)  { s = x;  d = xb;  off = id; }
    else if (id < 3686400) { s = wq; d = wqb; off = id - 737280; }
    else if (id < 4055040) { s = wk; d = wkb; off = id - 3686400; }
    else                   { s = wv; d = wvb; off = id - 4055040; }
    f32x4 v = *(const f32x4*)(s + (size_t)off * 4);
    union { u16 u[4]; unsigned long long ll; } o;
    #pragma unroll
    for (int j = 0; j < 4; ++j) o.u[j] = f2bf(v[j]);
    *(unsigned long long*)(d + (size_t)off * 4) = o.ll;
}

// ---------------------------------------------------------------------------
// NT GEMM, split-K, m97-EXACT structure (R10/R11: best measured, no spill).
// 256 threads, 4 waves of 64x64, 128x128 tile, BK=64, single 32 KB LDS buf,
// 2-barrier K-loop; pipelining = implicit cross-block wave overlap (~4/CU).
// bounds(256,3): no spill (VGPR 64 arch + 64 acc). XOR chunk swizzle.
// XCD map: 8 consecutive M-tiles of one N-stripe per XCD.
// Blocks with lin >= gemmx are streaming-cvt blocks (wo fp32->bf16, z==0).
// ---------------------------------------------------------------------------
__global__ __launch_bounds__(256, 3) void gemm_m97(
    const u16* __restrict__ A, int lda, int kit, int ntot, int gemmx,
    const u16* __restrict__ W0, int t0, int n0, int c0,
    const u16* __restrict__ W1, int t1, int n1, int c1,
    const u16* __restrict__ W2, int t2, int n2, int c2,
    u16* __restrict__ C, int ldc, long long cstride,
    const float* __restrict__ cvsrc, u16* __restrict__ cvdst, int cvblk)
{
    __shared__ u16 Als[128 * 64];
    __shared__ u16 Bls[128 * 64];

    const int lin = blockIdx.x;
    const int z   = blockIdx.z;

    if (lin >= gemmx) {                 // streaming-cvt block (wo fp32->bf16)
        if (z == 0 && cvblk > 0) {
            const int cb_  = lin - gemmx;           // 0..cvblk-1
            const int step = cvblk * 256;           // f32x4 stride
            int idx = cb_ * 256 + threadIdx.x;
            #pragma unroll 4
            for (int i = 0; i < 16; ++i) {
                f32x4 v = *(const f32x4*)(cvsrc + (size_t)idx * 4);
                union { u16 u[4]; unsigned long long ll; } o;
                #pragma unroll
                for (int j = 0; j < 4; ++j) o.u[j] = f2bf(v[j]);
                *(unsigned long long*)(cvdst + (size_t)idx * 4) = o.ll;
                idx += step;
            }
        }
        return;
    }

    const int xc  = lin & 7;
    const int mm  = lin >> 3;
    const int nbl = xc + 8 * (mm >> 3);
    const int yt  = mm & 7;
    if (nbl >= ntot) return;   // uniform per block; no barriers executed

    const int tid  = threadIdx.x;
    const int lane = tid & 63;
    const int wid  = tid >> 6;          // 0..3
    const int li   = lane & 15;
    const int lg   = lane >> 4;
    const int m0   = yt * 128;

    const u16* W; int nt0, nsz, cb;
    if (nbl < t0)           { W = W0; nt0 = nbl * 128;             nsz = n0; cb = c0; }
    else if (nbl < t0 + t1) { W = W1; nt0 = (nbl - t0) * 128;      nsz = n1; cb = c1; }
    else                    { W = W2; nt0 = (nbl - t0 - t1) * 128; nsz = n2; cb = c2; }

    const int S  = gridDim.z;
    const int it0 = (z * kit) / S;
    const int it1 = ((z + 1) * kit) / S;
    u16* Cp = C + (long long)z * cstride;

    const int wm = (wid >> 1) * 64;
    const int wn = (wid & 1) * 64;

    f32x4 acc[4][4];
    #pragma unroll
    for (int mi = 0; mi < 4; ++mi)
        #pragma unroll
        for (int ni = 0; ni < 4; ++ni)
            acc[mi][ni] = (f32x4){0.f, 0.f, 0.f, 0.f};

    const int srow = tid >> 3;                 // 0..31 (row within 32-row slab)
    const int slc  = (tid & 7) ^ (srow & 7);   // inverse-swizzled source chunk

    for (int it = it0; it < it1; ++it) {
        const int k0 = it * 64;
        #pragma unroll
        for (int s_ = 0; s_ < 4; ++s_) {
            const u16* sa = A + (size_t)(m0 + s_ * 32 + srow) * lda + k0 + slc * 8;
            GLOAD16(sa, &Als[(s_ * 256 + tid) * 8]);
        }
        #pragma unroll
        for (int s_ = 0; s_ < 4; ++s_) {
            int wr = nt0 + s_ * 32 + srow;
            if (wr > nsz - 1) wr = nsz - 1;    // ragged-N clamp (stores guarded)
            const u16* sb = W + (size_t)wr * lda + k0 + slc * 8;
            GLOAD16(sb, &Bls[(s_ * 256 + tid) * 8]);
        }
        __syncthreads();

        s16x8 af[4][2], bfv[4][2];
        #pragma unroll
        for (int mi = 0; mi < 4; ++mi)
            #pragma unroll
            for (int kc = 0; kc < 2; ++kc) {
                int row = wm + mi * 16 + li;
                int ch  = (kc * 4 + lg) ^ (row & 7);
                af[mi][kc] = *(const s16x8*)&Als[row * 64 + ch * 8];
            }
        #pragma unroll
        for (int ni = 0; ni < 4; ++ni)
            #pragma unroll
            for (int kc = 0; kc < 2; ++kc) {
                int row = wn + ni * 16 + li;
                int ch  = (kc * 4 + lg) ^ (row & 7);
                bfv[ni][kc] = *(const s16x8*)&Bls[row * 64 + ch * 8];
            }
        #pragma unroll
        for (int mi = 0; mi < 4; ++mi)
            #pragma unroll
            for (int ni = 0; ni < 4; ++ni)
                #pragma unroll
                for (int kc = 0; kc < 2; ++kc)
                    acc[mi][ni] = mfma_bf16(af[mi][kc], bfv[ni][kc], acc[mi][ni]);
        __syncthreads();
    }

    #pragma unroll
    for (int ni = 0; ni < 4; ++ni) {
        int colr = nt0 + wn + ni * 16 + li;
        if (colr < nsz) {
            #pragma unroll
            for (int mi = 0; mi < 4; ++mi)
                #pragma unroll
                for (int r = 0; r < 4; ++r) {
                    int row = m0 + wm + mi * 16 + lg * 4 + r;
                    Cp[(size_t)row * ldc + cb + colr] = f2bf(acc[mi][ni][r]);
                }
        }
    }
}

// ---------------------------------------------------------------------------
// RoPE + bias + bf16 convert from 3 bf16 split-K partials. Vectorized:
// each thread handles 8 consecutive dims (bf16x8 loads, 16B stores).
// Groups per row: 256 q (64 heads x 4 d-groups) + 32 k + 64 v = 352.
// ---------------------------------------------------------------------------
__global__ void rope_kernel(const u16* __restrict__ qkvp,
                            const float* __restrict__ qb, const float* __restrict__ kb,
                            const float* __restrict__ vb,
                            u16* __restrict__ qo, u16* __restrict__ ko, u16* __restrict__ vo)
{
    const long long PST = 1024LL * 5120;
    int id = blockIdx.x * 256 + threadIdx.x;   // 1024 * 352
    int s  = id / 352;
    int g  = id % 352;
    const u16* r0 = qkvp + (size_t)s * 5120;

    if (g < 288) {                      // q (g<256) or k
        bool isq = g < 256;
        int gg   = isq ? g : g - 256;
        int hh   = gg >> 2;
        int dg   = gg & 3;
        int col0 = (isq ? 0 : 4096) + hh * 64 + dg * 8;
        int bcol = isq ? col0 : col0 - 4096;
        const float* bias = isq ? qb : kb;

        float t1[8], t2[8];
        #pragma unroll
        for (int e = 0; e < 8; ++e) { t1[e] = bias[bcol + e]; t2[e] = bias[bcol + 32 + e]; }
        #pragma unroll
        for (int p = 0; p < 3; ++p) {
            s16x8 lo = *(const s16x8*)(r0 + col0 + p * PST);
            s16x8 hi = *(const s16x8*)(r0 + col0 + 32 + p * PST);
            #pragma unroll
            for (int e = 0; e < 8; ++e) {
                t1[e] += bf2f((u16)lo[e]);
                t2[e] += bf2f((u16)hi[e]);
            }
        }
        float sc = isq ? 0.125f : 1.0f;    // fold HD^-0.5 into q
        s16x8 o1, o2;
        #pragma unroll
        for (int e = 0; e < 8; ++e) {
            int d = dg * 8 + e;
            float ang = (float)s * exp2f((float)d * -0.5373314f);
            float sn, cs;
            sincosf(ang, &sn, &cs);
            o1[e] = (short)f2bf((t1[e] * cs - t2[e] * sn) * sc);
            o2[e] = (short)f2bf((t1[e] * sn + t2[e] * cs) * sc);
        }
        u16* dst = isq ? qo : ko;
        int ldd  = isq ? 4096 : 512;
        *(s16x8*)(dst + (size_t)s * ldd + bcol)      = o1;
        *(s16x8*)(dst + (size_t)s * ldd + bcol + 32) = o2;
    } else {                            // v: plain sum + bias
        int gg   = g - 288;             // 0..63
        int col0 = 4608 + gg * 8;
        float t[8];
        #pragma unroll
        for (int e = 0; e < 8; ++e) t[e] = vb[gg * 8 + e];
        #pragma unroll
        for (int p = 0; p < 3; ++p) {
            s16x8 v = *(const s16x8*)(r0 + col0 + p * PST);
            #pragma unroll
            for (int e = 0; e < 8; ++e) t[e] += bf2f((u16)v[e]);
        }
        s16x8 o;
        #pragma unroll
        for (int e = 0; e < 8; ++e) o[e] = (short)f2bf(t[e]);
        *(s16x8*)(vo + (size_t)s * 512 + gg * 8) = o;
    }
}

// ---------------------------------------------------------------------------
// out = sum of 4 bf16 split-K partials + bias (fp32)
// ---------------------------------------------------------------------------
__global__ void reduce_out_kernel(const u16* __restrict__ parts,
                                  const float* __restrict__ bias,
                                  float* __restrict__ out)
{
    int id = blockIdx.x * 256 + threadIdx.x;      // 0..368639 (8-elem groups)
    const long long stride = 1024LL * 2880;
    long long base = (long long)id * 8;
    float s[8];
    #pragma unroll
    for (int j = 0; j < 8; ++j) s[j] = 0.f;
    #pragma unroll
    for (int p = 0; p < 4; ++p) {
        s16x8 v = *(const s16x8*)(parts + p * stride + base);
        #pragma unroll
        for (int j = 0; j < 8; ++j) s[j] += bf2f((u16)v[j]);
    }
    int cb = (int)(base % 2880);
    f32x4 b0 = *(const f32x4*)(bias + cb);
    f32x4 b1 = *(const f32x4*)(bias + cb + 4);
    f32x4 o0 = {s[0] + b0[0], s[1] + b0[1], s[2] + b0[2], s[3] + b0[3]};
    f32x4 o1 = {s[4] + b1[0], s[5] + b1[1], s[6] + b1[2], s[7] + b1[3]};
    *(f32x4*)(out + base)     = o0;
    *(f32x4*)(out + base + 4) = o1;
}

// ---------------------------------------------------------------------------
// Sliding-window GQA attention with sinks (R10/R11 form: best-wall config).
// ---------------------------------------------------------------------------
__global__ __launch_bounds__(256, 2) void attn_kernel(
    const u16* __restrict__ Q, const u16* __restrict__ Kb, const u16* __restrict__ Vb,
    const float* __restrict__ sinks, u16* __restrict__ Ob)
{
    __shared__ u16 Kls[64 * 64];
    __shared__ u16 Pls[4][16 * 72];

    const int h    = blockIdx.x;
    const int qblk = blockIdx.y;
    const int kvh  = h >> 3;
    const int tid  = threadIdx.x;
    const int lane = tid & 63;
    const int w    = tid >> 6;
    const int li   = lane & 15;
    const int lg   = lane >> 4;
    const int qw   = qblk * 64 + w * 16;

    s16x8 aq[2];
    {
        const u16* qrow = Q + ((size_t)(qw + li) * 64 + h) * 64 + lg * 8;
        aq[0] = *(const s16x8*)(qrow);
        aq[1] = *(const s16x8*)(qrow + 32);
    }

    const float snk = sinks[h];
    float m_run[4], l_run[4];
    f32x4 oacc[4];
    #pragma unroll
    for (int r = 0; r < 4; ++r) { m_run[r] = snk; l_run[r] = 1.0f; }
    #pragma unroll
    for (int ni = 0; ni < 4; ++ni) oacc[ni] = (f32x4){0.f, 0.f, 0.f, 0.f};

    const int srow = tid >> 3;
    const int slc  = (tid & 7) ^ (srow & 7);

    for (int t = 0; t < 3; ++t) {
        int jt = qblk - 2 + t;
        if (jt < 0) continue;
        int j0 = jt * 64;

        #pragma unroll
        for (int it = 0; it < 2; ++it) {
            const u16* src = Kb + ((size_t)(j0 + it * 32 + srow) * 8 + kvh) * 64 + slc * 8;
            GLOAD16(src, &Kls[(it * 256 + w * 64) * 8]);
        }
        __syncthreads();

        f32x4 sc[4];
        #pragma unroll
        for (int nf = 0; nf < 4; ++nf) {
            sc[nf] = (f32x4){0.f, 0.f, 0.f, 0.f};
            #pragma unroll
            for (int kc = 0; kc < 2; ++kc) {
                int row = nf * 16 + li;
                int ch  = (kc * 4 + lg) ^ (row & 7);
                s16x8 bk = *(const s16x8*)&Kls[row * 64 + ch * 8];
                sc[nf] = mfma_bf16(aq[kc], bk, sc[nf]);
            }
        }

        #pragma unroll
        for (int r = 0; r < 4; ++r) {
            const int qg = qw + lg * 4 + r;
            float mx = -1e30f;
            #pragma unroll
            for (int nf = 0; nf < 4; ++nf) {
                int jg = j0 + nf * 16 + li;
                bool ok = (jg <= qg) && (qg - jg < 128);
                float v = ok ? sc[nf][r] : -1e30f;
                sc[nf][r] = v;
                mx = fmaxf(mx, v);
            }
            #pragma unroll
            for (int off = 1; off < 16; off <<= 1)
                mx = fmaxf(mx, __shfl_xor(mx, off));
            float mnew = fmaxf(m_run[r], mx);
            float corr = __expf(m_run[r] - mnew);
            m_run[r] = mnew;
            float rs = 0.f;
            #pragma unroll
            for (int nf = 0; nf < 4; ++nf) {
                float p = __expf(sc[nf][r] - mnew);
                rs += p;
                Pls[w][(lg * 4 + r) * 72 + nf * 16 + li] = f2bf(p);
            }
            #pragma unroll
            for (int off = 1; off < 16; off <<= 1)
                rs += __shfl_xor(rs, off);
            l_run[r] = l_run[r] * corr + rs;
            #pragma unroll
            for (int ni = 0; ni < 4; ++ni) oacc[ni][r] *= corr;
        }
        __syncthreads();   // all K reads done; P writes drained

        #pragma unroll
        for (int kc = 0; kc < 2; ++kc) {
            s16x8 pa = *(const s16x8*)&Pls[w][li * 72 + kc * 32 + lg * 8];
            #pragma unroll
            for (int ni = 0; ni < 4; ++ni) {
                const u16* vsrc = Vb + ((size_t)(j0 + kc * 32 + lg * 8) * 8 + kvh) * 64 + ni * 16 + li;
                s16x8 bv;
                #pragma unroll
                for (int i = 0; i < 8; ++i) bv[i] = (short)vsrc[(size_t)i * 512];
                oacc[ni] = mfma_bf16(pa, bv, oacc[ni]);
            }
        }
    }

    #pragma unroll
    for (int r = 0; r < 4; ++r) {
        float inv = 1.0f / l_run[r];
        #pragma unroll
        for (int ni = 0; ni < 4; ++ni)
            Ob[((size_t)(qw + lg * 4 + r) * 64 + h) * 64 + ni * 16 + li] = f2bf(oacc[ni][r] * inv);
    }
}

// ---------------------------------------------------------------------------
extern "C" void kernel_launch(void* const* d_in, const int* in_sizes, int n_in,
                              void* d_out, int out_size, void* d_ws, size_t ws_size,
                              hipStream_t stream)
{
    const float* x     = (const float*)d_in[0];
    const float* wq_w  = (const float*)d_in[1];
    const float* wq_b  = (const float*)d_in[2];
    const float* wk_w  = (const float*)d_in[3];
    const float* wk_b  = (const float*)d_in[4];
    const float* wv_w  = (const float*)d_in[5];
    const float* wv_b  = (const float*)d_in[6];
    const float* wo_w  = (const float*)d_in[7];
    const float* wo_b  = (const float*)d_in[8];
    const float* sinks = (const float*)d_in[9];

    char* ws = (char*)d_ws;
    // Layout (peak 112.1 MB; 117.9 proven available):
    //   [0, 35,389,440)           xb|wqb|wkb|wvb        (cvt1 -> gemm1)
    //       after rope overlays:  qr@0|kr|vbf|attb      (rope -> gemm2)
    //   [35,389,440, 66,846,720)  qkvp 3 bf16 partials  (gemm1 -> rope)
    //   [58,982,400, 88,473,600)  oprt 4 bf16 partials  (gemm2 -> reduce)
    //   [88,473,600, 112,066,560) wob                   (gemm1-launch cvt -> gemm2)
    u16*   xb   = (u16*)(ws + 0);
    u16*   wqb  = (u16*)(ws + 5898240ULL);
    u16*   wkb  = (u16*)(ws + 29491200ULL);
    u16*   wvb  = (u16*)(ws + 32440320ULL);
    u16*   qkvp = (u16*)(ws + 35389440ULL);      // 3 bf16 partials, stride 1024*5120
    u16*   qr   = (u16*)(ws + 0);
    u16*   kr   = (u16*)(ws + 8388608ULL);
    u16*   vbf  = (u16*)(ws + 9437184ULL);
    u16*   attb = (u16*)(ws + 10485760ULL);
    u16*   oprt = (u16*)(ws + 58982400ULL);      // 4 bf16 partials, stride 1024*2880
    u16*   wob  = (u16*)(ws + 88473600ULL);

    (void)in_sizes; (void)n_in; (void)out_size; (void)ws_size;

    // 1) bf16 conversions: x, wq, wk, wv (wo rides inside gemm1 launch)
    cvt1_kernel<<<17280, 256, 0, stream>>>(x, wq_w, wk_w, wv_w, xb, wqb, wkb, wvb);
    // 2) fused QKV projection, split-K=3 -> 3 bf16 partials [1024][5120]
    //    320 GEMM blocks + 720 streaming-cvt blocks (wo -> wob on z==0)
    gemm_m97<<<dim3(1040, 1, 3), 256, 0, stream>>>(xb, 2880, 45, 40, 320,
        wqb, 32, 4096, 0,
        wkb, 4, 512, 4096,
        wvb, 4, 512, 4608,
        qkvp, 5120, 1024LL * 5120,
        wo_w, wob, 720);
    // 3) RoPE + partial-sum + bias + convert (q pre-scaled by 0.125)
    rope_kernel<<<1408, 256, 0, stream>>>(qkvp, wq_b, wk_b, wv_b, qr, kr, vbf);
    // 4) attention -> attb bf16 [1024][4096]
    attn_kernel<<<dim3(64, 16), 256, 0, stream>>>(qr, kr, vbf, sinks, attb);
    // 5) output projection, split-K=4 -> 4 bf16 partials [1024][2880]
    gemm_m97<<<dim3(192, 1, 4), 256, 0, stream>>>(attb, 4096, 64, 23, 192,
        wob, 23, 2880, 0,
        wob, 0, 0, 0,
        wob, 0, 0, 0,
        oprt, 2880, 1024LL * 2880,
        (const float*)nullptr, (u16*)nullptr, 0);
    // 6) reduce 4 partials + bias -> d_out fp32 [1024][2880]
    reduce_out_kernel<<<1440, 256, 0, stream>>>(oprt, wo_b, (float*)d_out);
}

// Round 16
// 129.163 us; speedup vs baseline: 1.0594x; 1.0023x over previous
//
#include <hip/hip_runtime.h>

typedef __attribute__((ext_vector_type(4))) float f32x4;
typedef __attribute__((ext_vector_type(8))) short s16x8;
typedef unsigned short u16;

#define DEVI __device__ __forceinline__

// fp32 -> bf16 round-to-nearest-even
DEVI u16 f2bf(float f) {
    union { float f; unsigned int u; } v; v.f = f;
    unsigned int r = v.u + 0x7FFFu + ((v.u >> 16) & 1u);
    return (u16)(r >> 16);
}
DEVI float bf2f(u16 b) {
    union { unsigned int u; float f; } v; v.u = ((unsigned int)b) << 16;
    return v.f;
}

typedef __attribute__((address_space(1))) void gv_t;   // global
typedef __attribute__((address_space(3))) void sv_t;   // LDS

#define GLOAD16(SRC, DST) __builtin_amdgcn_global_load_lds( \
    (gv_t*)(SRC), (sv_t*)(DST), 16, 0, 0)

DEVI f32x4 mfma_bf16(s16x8 a, s16x8 b, f32x4 c) {
    return __builtin_amdgcn_mfma_f32_16x16x32_bf16(a, b, c, 0, 0, 0);
}

// ---------------------------------------------------------------------------
// fp32 -> bf16: x, wq, wk, wv only. wo is converted inside the ATTN launch
// (attn pulls <1 TB/s; R11 measured riders in gemm1 cost the full 11 us
// because gemm1 itself runs at 2.4 TB/s).
// ---------------------------------------------------------------------------
__global__ void cvt1_kernel(
    const float* __restrict__ x,  const float* __restrict__ wq, const float* __restrict__ wk,
    const float* __restrict__ wv,
    u16* __restrict__ xb, u16* __restrict__ wqb, u16* __restrict__ wkb,
    u16* __restrict__ wvb)
{
    int id = blockIdx.x * 256 + threadIdx.x;   // 0 .. 4423680-1 (f32x4 units)
    const float* s; u16* d; int off;
    if      (id < 737280)  { s = x;  d = xb;  off = id; }
    else if (id < 3686400) { s = wq; d = wqb; off = id - 737280; }
    else if (id < 4055040) { s = wk; d = wkb; off = id - 3686400; }
    else                   { s = wv; d = wvb; off = id - 4055040; }
    f32x4 v = *(const f32x4*)(s + (size_t)off * 4);
    union { u16 u[4]; unsigned long long ll; } o;
    #pragma unroll
    for (int j = 0; j < 4; ++j) o.u[j] = f2bf(v[j]);
    *(unsigned long long*)(d + (size_t)off * 4) = o.ll;
}

// ---------------------------------------------------------------------------
// NT GEMM, split-K, m97-EXACT structure (R10/R11/R15: best measured).
// 256 threads, 4 waves of 64x64, 128x128 tile, BK=64, single 32 KB LDS buf,
// 2-barrier K-loop; pipelining = implicit cross-block wave overlap (~4/CU).
// bounds(256,3): no spill (VGPR 64 arch + 64 acc). XOR chunk swizzle.
// XCD map: 8 consecutive M-tiles of one N-stripe per XCD.
// ---------------------------------------------------------------------------
__global__ __launch_bounds__(256, 3) void gemm_m97(
    const u16* __restrict__ A, int lda, int kit, int ntot,
    const u16* __restrict__ W0, int t0, int n0, int c0,
    const u16* __restrict__ W1, int t1, int n1, int c1,
    const u16* __restrict__ W2, int t2, int n2, int c2,
    u16* __restrict__ C, int ldc, long long cstride)
{
    __shared__ u16 Als[128 * 64];
    __shared__ u16 Bls[128 * 64];

    const int lin = blockIdx.x;
    const int xc  = lin & 7;
    const int mm  = lin >> 3;
    const int nbl = xc + 8 * (mm >> 3);
    const int yt  = mm & 7;
    if (nbl >= ntot) return;   // uniform per block; no barriers executed

    const int tid  = threadIdx.x;
    const int lane = tid & 63;
    const int wid  = tid >> 6;          // 0..3
    const int li   = lane & 15;
    const int lg   = lane >> 4;
    const int m0   = yt * 128;

    const u16* W; int nt0, nsz, cb;
    if (nbl < t0)           { W = W0; nt0 = nbl * 128;             nsz = n0; cb = c0; }
    else if (nbl < t0 + t1) { W = W1; nt0 = (nbl - t0) * 128;      nsz = n1; cb = c1; }
    else                    { W = W2; nt0 = (nbl - t0 - t1) * 128; nsz = n2; cb = c2; }

    const int z  = blockIdx.z;
    const int S  = gridDim.z;
    const int it0 = (z * kit) / S;
    const int it1 = ((z + 1) * kit) / S;
    u16* Cp = C + (long long)z * cstride;

    const int wm = (wid >> 1) * 64;
    const int wn = (wid & 1) * 64;

    f32x4 acc[4][4];
    #pragma unroll
    for (int mi = 0; mi < 4; ++mi)
        #pragma unroll
        for (int ni = 0; ni < 4; ++ni)
            acc[mi][ni] = (f32x4){0.f, 0.f, 0.f, 0.f};

    const int srow = tid >> 3;                 // 0..31 (row within 32-row slab)
    const int slc  = (tid & 7) ^ (srow & 7);   // inverse-swizzled source chunk

    for (int it = it0; it < it1; ++it) {
        const int k0 = it * 64;
        #pragma unroll
        for (int s_ = 0; s_ < 4; ++s_) {
            const u16* sa = A + (size_t)(m0 + s_ * 32 + srow) * lda + k0 + slc * 8;
            GLOAD16(sa, &Als[(s_ * 256 + tid) * 8]);
        }
        #pragma unroll
        for (int s_ = 0; s_ < 4; ++s_) {
            int wr = nt0 + s_ * 32 + srow;
            if (wr > nsz - 1) wr = nsz - 1;    // ragged-N clamp (stores guarded)
            const u16* sb = W + (size_t)wr * lda + k0 + slc * 8;
            GLOAD16(sb, &Bls[(s_ * 256 + tid) * 8]);
        }
        __syncthreads();

        s16x8 af[4][2], bfv[4][2];
        #pragma unroll
        for (int mi = 0; mi < 4; ++mi)
            #pragma unroll
            for (int kc = 0; kc < 2; ++kc) {
                int row = wm + mi * 16 + li;
                int ch  = (kc * 4 + lg) ^ (row & 7);
                af[mi][kc] = *(const s16x8*)&Als[row * 64 + ch * 8];
            }
        #pragma unroll
        for (int ni = 0; ni < 4; ++ni)
            #pragma unroll
            for (int kc = 0; kc < 2; ++kc) {
                int row = wn + ni * 16 + li;
                int ch  = (kc * 4 + lg) ^ (row & 7);
                bfv[ni][kc] = *(const s16x8*)&Bls[row * 64 + ch * 8];
            }
        #pragma unroll
        for (int mi = 0; mi < 4; ++mi)
            #pragma unroll
            for (int ni = 0; ni < 4; ++ni)
                #pragma unroll
                for (int kc = 0; kc < 2; ++kc)
                    acc[mi][ni] = mfma_bf16(af[mi][kc], bfv[ni][kc], acc[mi][ni]);
        __syncthreads();
    }

    #pragma unroll
    for (int ni = 0; ni < 4; ++ni) {
        int colr = nt0 + wn + ni * 16 + li;
        if (colr < nsz) {
            #pragma unroll
            for (int mi = 0; mi < 4; ++mi)
                #pragma unroll
                for (int r = 0; r < 4; ++r) {
                    int row = m0 + wm + mi * 16 + lg * 4 + r;
                    Cp[(size_t)row * ldc + cb + colr] = f2bf(acc[mi][ni][r]);
                }
        }
    }
}

// ---------------------------------------------------------------------------
// RoPE + bias + bf16 convert from 3 bf16 split-K partials. Vectorized:
// each thread handles 8 consecutive dims (bf16x8 loads, 16B stores).
// Groups per row: 256 q (64 heads x 4 d-groups) + 32 k + 64 v = 352.
// ---------------------------------------------------------------------------
__global__ void rope_kernel(const u16* __restrict__ qkvp,
                            const float* __restrict__ qb, const float* __restrict__ kb,
                            const float* __restrict__ vb,
                            u16* __restrict__ qo, u16* __restrict__ ko, u16* __restrict__ vo)
{
    const long long PST = 1024LL * 5120;
    int id = blockIdx.x * 256 + threadIdx.x;   // 1024 * 352
    int s  = id / 352;
    int g  = id % 352;
    const u16* r0 = qkvp + (size_t)s * 5120;

    if (g < 288) {                      // q (g<256) or k
        bool isq = g < 256;
        int gg   = isq ? g : g - 256;
        int hh   = gg >> 2;
        int dg   = gg & 3;
        int col0 = (isq ? 0 : 4096) + hh * 64 + dg * 8;
        int bcol = isq ? col0 : col0 - 4096;
        const float* bias = isq ? qb : kb;

        float t1[8], t2[8];
        #pragma unroll
        for (int e = 0; e < 8; ++e) { t1[e] = bias[bcol + e]; t2[e] = bias[bcol + 32 + e]; }
        #pragma unroll
        for (int p = 0; p < 3; ++p) {
            s16x8 lo = *(const s16x8*)(r0 + col0 + p * PST);
            s16x8 hi = *(const s16x8*)(r0 + col0 + 32 + p * PST);
            #pragma unroll
            for (int e = 0; e < 8; ++e) {
                t1[e] += bf2f((u16)lo[e]);
                t2[e] += bf2f((u16)hi[e]);
            }
        }
        float sc = isq ? 0.125f : 1.0f;    // fold HD^-0.5 into q
        s16x8 o1, o2;
        #pragma unroll
        for (int e = 0; e < 8; ++e) {
            int d = dg * 8 + e;
            float ang = (float)s * exp2f((float)d * -0.5373314f);
            float sn, cs;
            sincosf(ang, &sn, &cs);
            o1[e] = (short)f2bf((t1[e] * cs - t2[e] * sn) * sc);
            o2[e] = (short)f2bf((t1[e] * sn + t2[e] * cs) * sc);
        }
        u16* dst = isq ? qo : ko;
        int ldd  = isq ? 4096 : 512;
        *(s16x8*)(dst + (size_t)s * ldd + bcol)      = o1;
        *(s16x8*)(dst + (size_t)s * ldd + bcol + 32) = o2;
    } else {                            // v: plain sum + bias
        int gg   = g - 288;             // 0..63
        int col0 = 4608 + gg * 8;
        float t[8];
        #pragma unroll
        for (int e = 0; e < 8; ++e) t[e] = vb[gg * 8 + e];
        #pragma unroll
        for (int p = 0; p < 3; ++p) {
            s16x8 v = *(const s16x8*)(r0 + col0 + p * PST);
            #pragma unroll
            for (int e = 0; e < 8; ++e) t[e] += bf2f((u16)v[e]);
        }
        s16x8 o;
        #pragma unroll
        for (int e = 0; e < 8; ++e) o[e] = (short)f2bf(t[e]);
        *(s16x8*)(vo + (size_t)s * 512 + gg * 8) = o;
    }
}

// ---------------------------------------------------------------------------
// out = sum of 4 bf16 split-K partials + bias (fp32)
// ---------------------------------------------------------------------------
__global__ void reduce_out_kernel(const u16* __restrict__ parts,
                                  const float* __restrict__ bias,
                                  float* __restrict__ out)
{
    int id = blockIdx.x * 256 + threadIdx.x;      // 0..368639 (8-elem groups)
    const long long stride = 1024LL * 2880;
    long long base = (long long)id * 8;
    float s[8];
    #pragma unroll
    for (int j = 0; j < 8; ++j) s[j] = 0.f;
    #pragma unroll
    for (int p = 0; p < 4; ++p) {
        s16x8 v = *(const s16x8*)(parts + p * stride + base);
        #pragma unroll
        for (int j = 0; j < 8; ++j) s[j] += bf2f((u16)v[j]);
    }
    int cb = (int)(base % 2880);
    f32x4 b0 = *(const f32x4*)(bias + cb);
    f32x4 b1 = *(const f32x4*)(bias + cb + 4);
    f32x4 o0 = {s[0] + b0[0], s[1] + b0[1], s[2] + b0[2], s[3] + b0[3]};
    f32x4 o1 = {s[4] + b1[0], s[5] + b1[1], s[6] + b1[2], s[7] + b1[3]};
    *(f32x4*)(out + base)     = o0;
    *(f32x4*)(out + base + 4) = o1;
}

// ---------------------------------------------------------------------------
// Sliding-window GQA attention with sinks (R10/R11/R15 form) + wo-cvt
// riders: blocks x >= 64 (y==0 only) stream wo fp32->bf16 in attn's idle
// bandwidth. Attn blocks are bit-identical to the R15 version.
// ---------------------------------------------------------------------------
__global__ __launch_bounds__(256, 2) void attn_kernel(
    const u16* __restrict__ Q, const u16* __restrict__ Kb, const u16* __restrict__ Vb,
    const float* __restrict__ sinks, u16* __restrict__ Ob,
    const float* __restrict__ cvsrc, u16* __restrict__ cvdst)
{
    if (blockIdx.x >= 64) {             // wo-cvt rider (720 blocks on y==0)
        if (blockIdx.y == 0) {
            const int cb_  = blockIdx.x - 64;       // 0..719
            const int step = 720 * 256;             // f32x4 stride
            int idx = cb_ * 256 + threadIdx.x;
            #pragma unroll 4
            for (int i = 0; i < 16; ++i) {
                f32x4 v = *(const f32x4*)(cvsrc + (size_t)idx * 4);
                union { u16 u[4]; unsigned long long ll; } o;
                #pragma unroll
                for (int j = 0; j < 4; ++j) o.u[j] = f2bf(v[j]);
                *(unsigned long long*)(cvdst + (size_t)idx * 4) = o.ll;
                idx += step;
            }
        }
        return;
    }

    __shared__ u16 Kls[64 * 64];
    __shared__ u16 Pls[4][16 * 72];

    const int h    = blockIdx.x;
    const int qblk = blockIdx.y;
    const int kvh  = h >> 3;
    const int tid  = threadIdx.x;
    const int lane = tid & 63;
    const int w    = tid >> 6;
    const int li   = lane & 15;
    const int lg   = lane >> 4;
    const int qw   = qblk * 64 + w * 16;

    s16x8 aq[2];
    {
        const u16* qrow = Q + ((size_t)(qw + li) * 64 + h) * 64 + lg * 8;
        aq[0] = *(const s16x8*)(qrow);
        aq[1] = *(const s16x8*)(qrow + 32);
    }

    const float snk = sinks[h];
    float m_run[4], l_run[4];
    f32x4 oacc[4];
    #pragma unroll
    for (int r = 0; r < 4; ++r) { m_run[r] = snk; l_run[r] = 1.0f; }
    #pragma unroll
    for (int ni = 0; ni < 4; ++ni) oacc[ni] = (f32x4){0.f, 0.f, 0.f, 0.f};

    const int srow = tid >> 3;
    const int slc  = (tid & 7) ^ (srow & 7);

    for (int t = 0; t < 3; ++t) {
        int jt = qblk - 2 + t;
        if (jt < 0) continue;
        int j0 = jt * 64;

        #pragma unroll
        for (int it = 0; it < 2; ++it) {
            const u16* src = Kb + ((size_t)(j0 + it * 32 + srow) * 8 + kvh) * 64 + slc * 8;
            GLOAD16(src, &Kls[(it * 256 + w * 64) * 8]);
        }
        __syncthreads();

        f32x4 sc[4];
        #pragma unroll
        for (int nf = 0; nf < 4; ++nf) {
            sc[nf] = (f32x4){0.f, 0.f, 0.f, 0.f};
            #pragma unroll
            for (int kc = 0; kc < 2; ++kc) {
                int row = nf * 16 + li;
                int ch  = (kc * 4 + lg) ^ (row & 7);
                s16x8 bk = *(const s16x8*)&Kls[row * 64 + ch * 8];
                sc[nf] = mfma_bf16(aq[kc], bk, sc[nf]);
            }
        }

        #pragma unroll
        for (int r = 0; r < 4; ++r) {
            const int qg = qw + lg * 4 + r;
            float mx = -1e30f;
            #pragma unroll
            for (int nf = 0; nf < 4; ++nf) {
                int jg = j0 + nf * 16 + li;
                bool ok = (jg <= qg) && (qg - jg < 128);
                float v = ok ? sc[nf][r] : -1e30f;
                sc[nf][r] = v;
                mx = fmaxf(mx, v);
            }
            #pragma unroll
            for (int off = 1; off < 16; off <<= 1)
                mx = fmaxf(mx, __shfl_xor(mx, off));
            float mnew = fmaxf(m_run[r], mx);
            float corr = __expf(m_run[r] - mnew);
            m_run[r] = mnew;
            float rs = 0.f;
            #pragma unroll
            for (int nf = 0; nf < 4; ++nf) {
                float p = __expf(sc[nf][r] - mnew);
                rs += p;
                Pls[w][(lg * 4 + r) * 72 + nf * 16 + li] = f2bf(p);
            }
            #pragma unroll
            for (int off = 1; off < 16; off <<= 1)
                rs += __shfl_xor(rs, off);
            l_run[r] = l_run[r] * corr + rs;
            #pragma unroll
            for (int ni = 0; ni < 4; ++ni) oacc[ni][r] *= corr;
        }
        __syncthreads();   // all K reads done; P writes drained

        #pragma unroll
        for (int kc = 0; kc < 2; ++kc) {
            s16x8 pa = *(const s16x8*)&Pls[w][li * 72 + kc * 32 + lg * 8];
            #pragma unroll
            for (int ni = 0; ni < 4; ++ni) {
                const u16* vsrc = Vb + ((size_t)(j0 + kc * 32 + lg * 8) * 8 + kvh) * 64 + ni * 16 + li;
                s16x8 bv;
                #pragma unroll
                for (int i = 0; i < 8; ++i) bv[i] = (short)vsrc[(size_t)i * 512];
                oacc[ni] = mfma_bf16(pa, bv, oacc[ni]);
            }
        }
    }

    #pragma unroll
    for (int r = 0; r < 4; ++r) {
        float inv = 1.0f / l_run[r];
        #pragma unroll
        for (int ni = 0; ni < 4; ++ni)
            Ob[((size_t)(qw + lg * 4 + r) * 64 + h) * 64 + ni * 16 + li] = f2bf(oacc[ni][r] * inv);
    }
}

// ---------------------------------------------------------------------------
extern "C" void kernel_launch(void* const* d_in, const int* in_sizes, int n_in,
                              void* d_out, int out_size, void* d_ws, size_t ws_size,
                              hipStream_t stream)
{
    const float* x     = (const float*)d_in[0];
    const float* wq_w  = (const float*)d_in[1];
    const float* wq_b  = (const float*)d_in[2];
    const float* wk_w  = (const float*)d_in[3];
    const float* wk_b  = (const float*)d_in[4];
    const float* wv_w  = (const float*)d_in[5];
    const float* wv_b  = (const float*)d_in[6];
    const float* wo_w  = (const float*)d_in[7];
    const float* wo_b  = (const float*)d_in[8];
    const float* sinks = (const float*)d_in[9];

    char* ws = (char*)d_ws;
    // Layout (peak 112.1 MB; 117.9 proven available):
    //   [0, 35,389,440)           xb|wqb|wkb|wvb        (cvt1 -> gemm1)
    //       after rope overlays:  qr@0|kr|vbf|attb      (rope -> gemm2)
    //   [35,389,440, 66,846,720)  qkvp 3 bf16 partials  (gemm1 -> rope)
    //   [58,982,400, 88,473,600)  oprt 4 bf16 partials  (gemm2 -> reduce)
    //   [88,473,600, 112,066,560) wob                   (attn-launch cvt -> gemm2)
    u16*   xb   = (u16*)(ws + 0);
    u16*   wqb  = (u16*)(ws + 5898240ULL);
    u16*   wkb  = (u16*)(ws + 29491200ULL);
    u16*   wvb  = (u16*)(ws + 32440320ULL);
    u16*   qkvp = (u16*)(ws + 35389440ULL);      // 3 bf16 partials, stride 1024*5120
    u16*   qr   = (u16*)(ws + 0);
    u16*   kr   = (u16*)(ws + 8388608ULL);
    u16*   vbf  = (u16*)(ws + 9437184ULL);
    u16*   attb = (u16*)(ws + 10485760ULL);
    u16*   oprt = (u16*)(ws + 58982400ULL);      // 4 bf16 partials, stride 1024*2880
    u16*   wob  = (u16*)(ws + 88473600ULL);

    (void)in_sizes; (void)n_in; (void)out_size; (void)ws_size;

    // 1) bf16 conversions: x, wq, wk, wv
    cvt1_kernel<<<17280, 256, 0, stream>>>(x, wq_w, wk_w, wv_w, xb, wqb, wkb, wvb);
    // 2) fused QKV projection, split-K=3 -> 3 bf16 partials [1024][5120]
    //    pure GEMM grid (960 blocks, ~4/CU): R10-verified ~47 us
    gemm_m97<<<dim3(320, 1, 3), 256, 0, stream>>>(xb, 2880, 45, 40,
        wqb, 32, 4096, 0,
        wkb, 4, 512, 4096,
        wvb, 4, 512, 4608,
        qkvp, 5120, 1024LL * 5120);
    // 3) RoPE + partial-sum + bias + convert (q pre-scaled by 0.125)
    rope_kernel<<<1408, 256, 0, stream>>>(qkvp, wq_b, wk_b, wv_b, qr, kr, vbf);
    // 4) attention + wo-cvt riders -> attb bf16 [1024][4096]
    //    grid: 64 attn heads + 720 riders (y==0) x 16 q-blocks
    attn_kernel<<<dim3(784, 16), 256, 0, stream>>>(qr, kr, vbf, sinks, attb,
                                                   wo_w, wob);
    // 5) output projection, split-K=4 -> 4 bf16 partials [1024][2880]
    gemm_m97<<<dim3(192, 1, 4), 256, 0, stream>>>(attb, 4096, 64, 23,
        wob, 23, 2880, 0,
        wob, 0, 0, 0,
        wob, 0, 0, 0,
        oprt, 2880, 1024LL * 2880);
    // 6) reduce 4 partials + bias -> d_out fp32 [1024][2880]
    reduce_out_kernel<<<1440, 256, 0, stream>>>(oprt, wo_b, (float*)d_out);
}